// Round 3
// baseline (234.827 us; speedup 1.0000x reference)
//
#include <hip/hip_runtime.h>

// VQ argmin: x [16,64,64,64] NCHW fp32, codebook [1024,64] fp32.
// N = 16*64*64 = 65536 rows (b,h,w), D=64 channels, K=1024 codes.
// dist = ||e_k||^2 - 2*x.e_k  (||x||^2 dropped: row-constant, argmin-invariant)
//
// R3: R1/R2 had VGPR_Count=36 -> xv[64] array was demoted to SCRATCH by SROA
// (runs before unrolling; dynamic indices at SROA time). Fix: 64 NAMED scalar
// floats (macro-generated) so SROA can't demote and regalloc has no reason to
// spill (pressure ~80 < 128 budget from launch_bounds(256,4)). Also fold the
// e-norm pass into this kernel via LDS to kill the second launch.

#define K_CODES 1024
#define D_DIM   64
#define HW      4096   // 64*64

#define REP64(M) \
  M(0)  M(1)  M(2)  M(3)  M(4)  M(5)  M(6)  M(7)  \
  M(8)  M(9)  M(10) M(11) M(12) M(13) M(14) M(15) \
  M(16) M(17) M(18) M(19) M(20) M(21) M(22) M(23) \
  M(24) M(25) M(26) M(27) M(28) M(29) M(30) M(31) \
  M(32) M(33) M(34) M(35) M(36) M(37) M(38) M(39) \
  M(40) M(41) M(42) M(43) M(44) M(45) M(46) M(47) \
  M(48) M(49) M(50) M(51) M(52) M(53) M(54) M(55) \
  M(56) M(57) M(58) M(59) M(60) M(61) M(62) M(63)

__global__ __launch_bounds__(256, 4) void vq_kernel(const float* __restrict__ x,
                                                    const float* __restrict__ cb,
                                                    int* __restrict__ out) {
    const int tid = threadIdx.x;
    const int r = tid & 63;                                        // row within block
    const int quarter = __builtin_amdgcn_readfirstlane(tid >> 6);  // wave id, uniform
    const int n = blockIdx.x * 64 + r;
    const int b = n >> 12;          // n / 4096
    const int hw = n & (HW - 1);

    // ---- in-kernel codebook norms: thread tid does codes tid, tid+256, ... ----
    __shared__ float sE[K_CODES];
    {
#pragma unroll
        for (int q = 0; q < 4; ++q) {
            const int k = q * 256 + tid;
            const float4* row = (const float4*)(cb + (size_t)k * D_DIM);
            float s = 0.f;
#pragma unroll
            for (int i = 0; i < D_DIM / 4; ++i) {
                float4 v = row[i];
                s = fmaf(v.x, v.x, s);
                s = fmaf(v.y, v.y, s);
                s = fmaf(v.z, v.z, s);
                s = fmaf(v.w, v.w, s);
            }
            sE[k] = s;
        }
    }

    // ---- load this row's 64 channels into 64 NAMED registers ----
    const float* xb = x + (size_t)b * D_DIM * HW + hw;
#define XLOAD(d) float x##d = xb[(size_t)(d) * HW];
    REP64(XLOAD)
#undef XLOAD

    __syncthreads();   // sE ready

    float best = __builtin_inff();
    int bestk = 0;
    const int kbase = quarter * (K_CODES / 4);

#pragma unroll 1
    for (int kk = 0; kk < K_CODES / 4; kk += 4) {
        const int k = kbase + kk;                   // wave-uniform
        const float* __restrict__ e0 = cb + (size_t)k * D_DIM;
        const float* __restrict__ e1 = e0 + D_DIM;
        const float* __restrict__ e2 = e0 + 2 * D_DIM;
        const float* __restrict__ e3 = e0 + 3 * D_DIM;
        float a0 = 0.f, a1 = 0.f, a2 = 0.f, a3 = 0.f;
#define FMAD(d) \
        a0 = fmaf(e0[d], x##d, a0); \
        a1 = fmaf(e1[d], x##d, a1); \
        a2 = fmaf(e2[d], x##d, a2); \
        a3 = fmaf(e3[d], x##d, a3);
        REP64(FMAD)
#undef FMAD
        const float d0 = fmaf(-2.f, a0, sE[k]);
        const float d1 = fmaf(-2.f, a1, sE[k + 1]);
        const float d2 = fmaf(-2.f, a2, sE[k + 2]);
        const float d3 = fmaf(-2.f, a3, sE[k + 3]);
        // strict < and ascending k -> numpy argmin first-occurrence semantics
        if (d0 < best) { best = d0; bestk = k; }
        if (d1 < best) { best = d1; bestk = k + 1; }
        if (d2 < best) { best = d2; bestk = k + 2; }
        if (d3 < best) { best = d3; bestk = k + 3; }
    }

    // Combine the 4 K-quarters per row. Lower quarter wins ties (lower k).
    __shared__ float sd[256];
    __shared__ int   si[256];
    sd[tid] = best;
    si[tid] = bestk;
    __syncthreads();
    if (quarter == 0) {
#pragma unroll
        for (int q = 1; q < 4; ++q) {
            const float o = sd[q * 64 + r];
            const int  oi = si[q * 64 + r];
            if (o < best) { best = o; bestk = oi; }
        }
        out[n] = bestk;
    }
}

extern "C" void kernel_launch(void* const* d_in, const int* in_sizes, int n_in,
                              void* d_out, int out_size, void* d_ws, size_t ws_size,
                              hipStream_t stream) {
    const float* x  = (const float*)d_in[0];   // [16,64,64,64] fp32
    const float* cb = (const float*)d_in[1];   // [1024,64] fp32
    int*   out   = (int*)d_out;                // 65536 int32 indices

    vq_kernel<<<dim3(65536 / 64), dim3(256), 0, stream>>>(x, cb, out);
}

// Round 4
// 208.197 us; speedup vs baseline: 1.1279x; 1.1279x over previous
//
#include <hip/hip_runtime.h>

// VQ argmin: x [16,64,64,64] NCHW fp32, codebook [1024,64] fp32.
// N = 65536 rows, D = 64, K = 1024. dist = ||e||^2 - 2 x.e (||x||^2 dropped).
//
// R4: R1-R3 all failed to keep the 64-float x row in VGPRs (VGPR_Count 36/48:
// SROA scratch demotion, then load REMATERIALIZATION into the loop). New
// structure sidesteps regalloc: x tile lives in LDS (padded, conflict-free
// b128), each thread register-blocks 8 codes (8 accumulators, ~25 VGPRs of
// long-lived state). Codebook rides the scalar pipe (wave-uniform s_load).

#define K_CODES 1024
#define D_DIM   64
#define HW      4096   // 64*64
#define ROWS    64     // rows per block
#define PAD     68     // padded LDS row stride (floats): +16B -> bank group (r+c)%8

__global__ __launch_bounds__(256) void enorm_kernel(const float* __restrict__ cb,
                                                    float* __restrict__ enorm) {
    int k = blockIdx.x * 256 + threadIdx.x;   // grid 4x256 -> 1024
    const float4* row = (const float4*)(cb + (size_t)k * D_DIM);
    float s = 0.f;
#pragma unroll
    for (int i = 0; i < D_DIM / 4; ++i) {
        float4 v = row[i];
        s = fmaf(v.x, v.x, s);
        s = fmaf(v.y, v.y, s);
        s = fmaf(v.z, v.z, s);
        s = fmaf(v.w, v.w, s);
    }
    enorm[k] = s;
}

// 8-codes-at-a-time: 4 fmacs per code per x-chunk, macro-expanded so all
// accumulators are named scalars (static, SROA-proof).
#define CODE(c, dc) { const float4 ev = *(const float4*)(e + (c) * D_DIM + (dc) * 4); \
    a##c = fmaf(x4.x, ev.x, a##c); a##c = fmaf(x4.y, ev.y, a##c); \
    a##c = fmaf(x4.z, ev.z, a##c); a##c = fmaf(x4.w, ev.w, a##c); }

#define CHUNK(dc) { const float4 x4 = *(const float4*)(xrow + (dc) * 4); \
    CODE(0, dc) CODE(1, dc) CODE(2, dc) CODE(3, dc) \
    CODE(4, dc) CODE(5, dc) CODE(6, dc) CODE(7, dc) }

__global__ __launch_bounds__(256, 4) void vq_kernel(const float* __restrict__ x,
                                                    const float* __restrict__ cb,
                                                    const float* __restrict__ enorm,
                                                    int* __restrict__ out) {
    __shared__ float xs[ROWS * PAD];
    __shared__ float sd[256];
    __shared__ int   si[256];

    const int tid = threadIdx.x;
    const int r = tid & 63;                                        // row in tile
    const int quarter = __builtin_amdgcn_readfirstlane(tid >> 6);  // wave id, uniform
    const int n0 = blockIdx.x * ROWS;   // 64 | 4096 -> whole block same b
    const int b = n0 >> 12;
    const int hw0 = n0 & (HW - 1);

    // ---- stage x tile: wave q loads channels d = q*16..q*16+15 of all rows.
    // Global: lane r reads x[b][d][hw0+r] -> 64 consecutive floats, coalesced.
    // LDS write b128: bank group (r + chunk) % 8 -> conflict-free.
    {
        const float* g = x + ((size_t)b * D_DIM + quarter * 16) * HW + hw0 + r;
        float v[16];
#pragma unroll
        for (int i = 0; i < 16; ++i) v[i] = g[(size_t)i * HW];
#pragma unroll
        for (int j = 0; j < 4; ++j) {
            *(float4*)(&xs[r * PAD + (quarter * 4 + j) * 4]) =
                make_float4(v[4 * j], v[4 * j + 1], v[4 * j + 2], v[4 * j + 3]);
        }
    }
    __syncthreads();

    const float* xrow = &xs[r * PAD];
    float best = __builtin_inff();
    int bestk = 0;

#pragma unroll 1
    for (int t = 0; t < 32; ++t) {                 // 32 tiles x 8 codes = 256
        const int k0 = quarter * 256 + t * 8;      // wave-uniform
        const float* __restrict__ e = cb + (size_t)k0 * D_DIM;
        float a0 = 0.f, a1 = 0.f, a2 = 0.f, a3 = 0.f;
        float a4 = 0.f, a5 = 0.f, a6 = 0.f, a7 = 0.f;
        CHUNK(0)  CHUNK(1)  CHUNK(2)  CHUNK(3)
        CHUNK(4)  CHUNK(5)  CHUNK(6)  CHUNK(7)
        CHUNK(8)  CHUNK(9)  CHUNK(10) CHUNK(11)
        CHUNK(12) CHUNK(13) CHUNK(14) CHUNK(15)
        // finalize: dist = E - 2*a ; strict < + ascending k = numpy semantics
#define FIN(c) { const float dd = fmaf(-2.f, a##c, enorm[k0 + (c)]); \
                 if (dd < best) { best = dd; bestk = k0 + (c); } }
        FIN(0) FIN(1) FIN(2) FIN(3) FIN(4) FIN(5) FIN(6) FIN(7)
#undef FIN
    }

    // Combine 4 K-quarters per row; lower quarter (lower k) wins ties.
    sd[tid] = best;
    si[tid] = bestk;
    __syncthreads();
    if (quarter == 0) {
#pragma unroll
        for (int q = 1; q < 4; ++q) {
            const float o = sd[q * 64 + r];
            const int  oi = si[q * 64 + r];
            if (o < best) { best = o; bestk = oi; }
        }
        out[n0 + r] = bestk;
    }
}

extern "C" void kernel_launch(void* const* d_in, const int* in_sizes, int n_in,
                              void* d_out, int out_size, void* d_ws, size_t ws_size,
                              hipStream_t stream) {
    const float* x  = (const float*)d_in[0];   // [16,64,64,64] fp32
    const float* cb = (const float*)d_in[1];   // [1024,64] fp32
    float* enorm = (float*)d_ws;               // 1024 floats scratch
    int*   out   = (int*)d_out;                // 65536 int32 indices

    enorm_kernel<<<dim3(K_CODES / 256), dim3(256), 0, stream>>>(cb, enorm);
    vq_kernel<<<dim3(65536 / ROWS), dim3(256), 0, stream>>>(x, cb, enorm, out);
}